// Round 7
// baseline (192.943 us; speedup 1.0000x reference)
//
#include <hip/hip_runtime.h>

#define HH 128
#define WW 128
#define CC 64
#define CO 64
#define BB 4
#define GG 8
#define CG 8
#define KK 9
#define HW (HH*WW)

typedef __attribute__((ext_vector_type(8))) short short8;
typedef __attribute__((ext_vector_type(4))) float floatx4;
typedef __attribute__((ext_vector_type(2))) float f32x2;

union S8I { short8 s; int i[4]; };
union FU { float f; unsigned u; };

__device__ inline short f2bf(float f) {
    FU v; v.f = f;
    return (short)((v.u + 0x7FFF + ((v.u >> 16) & 1)) >> 16);
}
__device__ inline unsigned rnd2(float f) {   // round-half-up bf16 in bits [31:16]
    FU v; v.f = f;
    return v.u + 0x8000u;
}
__device__ inline float bflo(int e) { union { int i; float f; } u; u.i = e << 16; return u.f; }
__device__ inline float bfhi(int e) { union { int i; float f; } u; u.i = e & 0xffff0000; return u.f; }

// ---- merged prep (unchanged) ----
// A-frag layout for the half-K GEMM: fid = (h*9+gc)*4 + ot,
//   wf[fid*512 + L*8 + j] = bf16(W[o=ot*16+(L&15)][g=h*4+(L>>4)][cg=j][kk=gc])
// Input NCHW f32 -> in_t[b][g][y*W+x][cg] bf16 (16B per pixel-group).
__global__ __launch_bounds__(256)
void prep(const float* __restrict__ wt, const float* __restrict__ in,
          short* __restrict__ wf, short* __restrict__ in_t) {
    const int bid = blockIdx.x;
    if (bid < 144) {
        const int tid = bid * 256 + threadIdx.x;   // < 36864 = 576*64
        const int j   = tid & 7;
        const int L   = (tid >> 3) & 63;
        const int fid = tid >> 9;                  // (h*9+gc)*4 + ot, 0..71
        const int ot  = fid & 3;
        const int gch = fid >> 2;                  // h*9 + gc, 0..17
        const int h   = gch / 9, gc = gch - h * 9;
        const int o   = ot * 16 + (L & 15);
        const int g   = h * 4 + (L >> 4);
        wf[tid] = f2bf(wt[o * 576 + (g * 8 + j) * 9 + gc]);
    } else {
        const int idx = bid - 144;                 // 2048 blocks: 64 x 8 x 4
        const int bx = idx & 63;
        const int g  = (idx >> 6) & 7;
        const int b  = idx >> 9;
        const int p  = bx * 256 + threadIdx.x;
        const float* src = in + (b * CC + g * CG) * HW + p;
        short8 v;
        #pragma unroll
        for (int cg = 0; cg < CG; ++cg) v[cg] = f2bf(src[cg * HW]);
        *(short8*)(in_t + ((b * GG + g) * HW + p) * 8) = v;
    }
}

// v7: SPLIT-K ACROSS WAVES -> 2x grid parallelism.
// Finding (r0-r6): six schedules (LDS-transpose, B-direct, reg-batch, fenced
// batch, LDS-tile gather) all converge at 43-48us with every pipe <35% busy.
// The invariant: grid = 1024 blocks x 4 waves = 16 waves/CU (50% static cap)
// -- occupancy was GRID-capped all along; a latency-bound kernel at ~3
// waves/SIMD can't hide anything, so schedule didn't matter.
// Fix: split the two K-halves across wave PAIRS in the same block.
//   wave w: h = w>>1 (which 4-group K-half), strip = w&1 (which 16px).
//   Block = 32 px x full K, 256 thr; grid = 4b x 128ho x 4pxg = 2048 blocks
//   = 8192 waves = 32 waves/CU (100% static cap), per-wave path HALVED.
// Partials combine via an 8KB conflict-free LDS buffer (1 barrier); h=0
// waves add bias and store. Inner loop = plain per-tap (r1 form): at 8
// waves/SIMD TLP hides the per-tap gather/afr latency that killed r1 at 2.8.
__global__ __launch_bounds__(256, 8)
void dcn_split(const short* __restrict__ in_t, const float* __restrict__ off,
               const float* __restrict__ msk, const short* __restrict__ wf,
               const float* __restrict__ bias, float* __restrict__ out)
{
    __shared__ float s_red[2][16][64];   // 8192 B: h=1 partial accumulators

    const int t = threadIdx.x;

    // bijective XCD swizzle (2048 % 8 == 0): each XCD gets 256 contiguous tiles
    const int lin = (blockIdx.x & 7) * 256 + (blockIdx.x >> 3);
    const int b   = lin >> 9;          // 0..3
    const int rem = lin & 511;
    const int ho  = rem >> 2;          // 0..127
    const int bxg = rem & 3;           // 0..3: 32-px group

    const int w = t >> 6, lane = t & 63;
    const int h     = w >> 1;          // this wave's K-half (offset groups h*4..h*4+3)
    const int strip = w & 1;           // which 16-px strip of the 32
    const int q4 = lane >> 4, n16 = lane & 15;
    const int px = bxg * 32 + strip * 16 + n16;
    const int basepix = ho * WW + px;

    floatx4 acc[4];
    #pragma unroll
    for (int ot = 0; ot < 4; ++ot)
        #pragma unroll
        for (int r = 0; r < 4; ++r)
            acc[ot][r] = h ? 0.f : bias[ot * 16 + q4 * 4 + r];

    const char* ib = (const char*)(in_t + (long)b * GG * HW * 8);

    const int g   = h * 4 + q4;        // per-LANE offset group (B-frag k-block)
    const int gsh = g << 18;

    // ---- preload off/mask for this wave's 9 taps: 27 coalesced loads ----
    float pdy[9], pdx[9], pm[9];
    #pragma unroll
    for (int i = 0; i < 9; ++i) {
        const int offc = (b * 144 + g * 18 + i * 2) * HW + basepix;
        pdy[i] = off[offc];
        pdx[i] = off[offc + HW];
        pm[i]  = msk[(b * 72 + g * 9 + i) * HW + basepix];
    }

    // ---- 9 taps: gather -> interp -> B-frag -> 4 MFMA (compiler-scheduled) ----
    #pragma unroll
    for (int i = 0; i < 9; ++i) {
        const int ky = i / 3, kx = i - (i / 3) * 3;   // compile-time consts

        const float py  = (float)(ho - 1 + ky) + pdy[i];
        const float pxf = (float)(px - 1 + kx) + pdx[i];
        const float y0f = floorf(py), x0f = floorf(pxf);
        const float ly = py - y0f, lx = pxf - x0f;
        const int y0 = (int)y0f, x0 = (int)x0f;
        const int y1 = y0 + 1,  x1 = x0 + 1;

        const float vy0 = (y0 >= 0 && y0 < HH) ? 1.f : 0.f;
        const float vy1 = (y1 >= 0 && y1 < HH) ? 1.f : 0.f;
        const float vx0 = (x0 >= 0 && x0 < WW) ? 1.f : 0.f;
        const float vx1 = (x1 >= 0 && x1 < WW) ? 1.f : 0.f;
        const int y0c = min(max(y0, 0), HH - 1), y1c = min(max(y1, 0), HH - 1);
        const int x0c = min(max(x0, 0), WW - 1), x1c = min(max(x1, 0), WW - 1);

        const float m = pm[i];
        const float wy0 = (1.f - ly) * vy0 * m;
        const float wy1 = ly * vy1 * m;
        const float wx0 = (1.f - lx) * vx0;
        const float wx1 = lx * vx1;
        const float w00 = wy0 * wx0, w01 = wy0 * wx1;
        const float w10 = wy1 * wx0, w11 = wy1 * wx1;

        const int y0sh = gsh + (y0c << 11), y1sh = gsh + (y1c << 11);
        const int x0sh = x0c << 4, x1sh = x1c << 4;
        S8I u00, u01, u10, u11;
        u00.s = *(const short8*)(ib + (y0sh + x0sh));
        u01.s = *(const short8*)(ib + (y0sh + x1sh));
        u10.s = *(const short8*)(ib + (y1sh + x0sh));
        u11.s = *(const short8*)(ib + (y1sh + x1sh));

        const f32x2 W00 = {w00, w00}, W01 = {w01, w01};
        const f32x2 W10 = {w10, w10}, W11 = {w11, w11};
        S8I res;
        #pragma unroll
        for (int pc = 0; pc < 4; ++pc) {
            const int e00 = u00.i[pc], e01 = u01.i[pc];
            const int e10 = u10.i[pc], e11 = u11.i[pc];
            f32x2 a00 = {bflo(e00), bfhi(e00)};
            f32x2 a01 = {bflo(e01), bfhi(e01)};
            f32x2 a10 = {bflo(e10), bfhi(e10)};
            f32x2 a11 = {bflo(e11), bfhi(e11)};
            f32x2 v = a00 * W00;
            v += a01 * W01;
            v += a10 * W10;
            v += a11 * W11;
            res.i[pc] = (int)__builtin_amdgcn_perm(rnd2(v.y), rnd2(v.x), 0x07060302u);
        }

        // res.s IS the B-fragment for chunk (h,i); A-frags L2-hot global
        #pragma unroll
        for (int ot = 0; ot < 4; ++ot) {
            const short8 afr = *(const short8*)&wf[((h * 9 + i) * 4 + ot) * 512 + lane * 8];
            acc[ot] = __builtin_amdgcn_mfma_f32_16x16x32_bf16(afr, res.s, acc[ot], 0, 0, 0);
        }
    }

    // ---- combine K-halves: h=1 partials through LDS (conflict-free b32) ----
    if (h) {
        #pragma unroll
        for (int ot = 0; ot < 4; ++ot)
            #pragma unroll
            for (int r = 0; r < 4; ++r)
                s_red[strip][ot * 4 + r][lane] = acc[ot][r];
    }
    __syncthreads();
    if (!h) {
        #pragma unroll
        for (int ot = 0; ot < 4; ++ot)
            #pragma unroll
            for (int r = 0; r < 4; ++r)
                acc[ot][r] += s_red[strip][ot * 4 + r][lane];

        // ---- epilogue: o = ot*16 + q4*4 + r ----
        #pragma unroll
        for (int ot = 0; ot < 4; ++ot)
            #pragma unroll
            for (int r = 0; r < 4; ++r)
                out[((b * CO + ot * 16 + q4 * 4 + r) * HH + ho) * WW + px] = acc[ot][r];
    }
}

extern "C" void kernel_launch(void* const* d_in, const int* in_sizes, int n_in,
                              void* d_out, int out_size, void* d_ws, size_t ws_size,
                              hipStream_t stream) {
    const float* in   = (const float*)d_in[0];
    const float* off  = (const float*)d_in[1];
    const float* msk  = (const float*)d_in[2];
    const float* wt   = (const float*)d_in[3];
    const float* bias = (const float*)d_in[4];
    float* out = (float*)d_out;
    short* wf   = (short*)d_ws;            // 36864 shorts = 72 KB
    short* in_t = (short*)d_ws + 36864;    // 4*8*16384*8 shorts = 8 MB

    prep<<<144 + 2048, 256, 0, stream>>>(wt, in, wf, in_t);

    dcn_split<<<2048, 256, 0, stream>>>(in_t, off, msk, wf, bias, out);
}

// Round 8
// 155.000 us; speedup vs baseline: 1.2448x; 1.2448x over previous
//
#include <hip/hip_runtime.h>

#define HH 128
#define WW 128
#define CC 64
#define CO 64
#define BB 4
#define GG 8
#define CG 8
#define KK 9
#define HW (HH*WW)

typedef __attribute__((ext_vector_type(8))) short short8;
typedef __attribute__((ext_vector_type(4))) float floatx4;
typedef __attribute__((ext_vector_type(2))) float f32x2;

union S8I { short8 s; int i[4]; };
union FU { float f; unsigned u; };

__device__ inline short f2bf(float f) {
    FU v; v.f = f;
    return (short)((v.u + 0x7FFF + ((v.u >> 16) & 1)) >> 16);
}
__device__ inline unsigned rnd2(float f) {   // round-half-up bf16 in bits [31:16]
    FU v; v.f = f;
    return v.u + 0x8000u;
}
__device__ inline float bflo(int e) { union { int i; float f; } u; u.i = e << 16; return u.f; }
__device__ inline float bfhi(int e) { union { int i; float f; } u; u.i = e & 0xffff0000; return u.f; }

// ---- merged prep (unchanged) ----
// A-frag layout for the half-K GEMM: fid = (h*9+gc)*4 + ot,
//   wf[fid*512 + L*8 + j] = bf16(W[o=ot*16+(L&15)][g=h*4+(L>>4)][cg=j][kk=gc])
// Input NCHW f32 -> in_t[b][g][y*W+x][cg] bf16 (16B per pixel-group).
__global__ __launch_bounds__(256)
void prep(const float* __restrict__ wt, const float* __restrict__ in,
          short* __restrict__ wf, short* __restrict__ in_t) {
    const int bid = blockIdx.x;
    if (bid < 144) {
        const int tid = bid * 256 + threadIdx.x;   // < 36864 = 576*64
        const int j   = tid & 7;
        const int L   = (tid >> 3) & 63;
        const int fid = tid >> 9;                  // (h*9+gc)*4 + ot, 0..71
        const int ot  = fid & 3;
        const int gch = fid >> 2;                  // h*9 + gc, 0..17
        const int h   = gch / 9, gc = gch - h * 9;
        const int o   = ot * 16 + (L & 15);
        const int g   = h * 4 + (L >> 4);
        wf[tid] = f2bf(wt[o * 576 + (g * 8 + j) * 9 + gc]);
    } else {
        const int idx = bid - 144;                 // 2048 blocks: 64 x 8 x 4
        const int bx = idx & 63;
        const int g  = (idx >> 6) & 7;
        const int b  = idx >> 9;
        const int p  = bx * 256 + threadIdx.x;
        const float* src = in + (b * CC + g * CG) * HW + p;
        short8 v;
        #pragma unroll
        for (int cg = 0; cg < CG; ++cg) v[cg] = f2bf(src[cg * HW]);
        *(short8*)(in_t + ((b * GG + g) * HW + p) * 8) = v;
    }
}

// v8: SPILL-FREE split-K across waves.
// r7 reached 60% occupancy (first time past the 50% static cap every earlier
// round silently had) but __launch_bounds__(256,8) forced a 64-VGPR cap the
// ~75-reg live set couldn't fit -> scratch spills (WRITE 16->70MB, FETCH
// 32->56MB, VGPR=32) -> 101us. The parallelism test never ran fairly.
// Fixes: (a) off/mask loaded PER TAP (kills the 27-reg preload; loads are
// coalesced and L3-warm); (b) __launch_bounds__(256,6) -> ~84 VGPR budget,
// live set ~60 fits with headroom, zero spill; static cap 24 waves/CU (75%).
// Spill detector for the post-mortem: WRITE_SIZE must be back at ~16.4MB.
__global__ __launch_bounds__(256, 6)
void dcn_split(const short* __restrict__ in_t, const float* __restrict__ off,
               const float* __restrict__ msk, const short* __restrict__ wf,
               const float* __restrict__ bias, float* __restrict__ out)
{
    __shared__ float s_red[2][16][64];   // 8192 B: h=1 partial accumulators

    const int t = threadIdx.x;

    // bijective XCD swizzle (2048 % 8 == 0)
    const int lin = (blockIdx.x & 7) * 256 + (blockIdx.x >> 3);
    const int b   = lin >> 9;          // 0..3
    const int rem = lin & 511;
    const int ho  = rem >> 2;          // 0..127
    const int bxg = rem & 3;           // 0..3: 32-px group

    const int w = t >> 6, lane = t & 63;
    const int h     = w >> 1;          // this wave's K-half (groups h*4..h*4+3)
    const int strip = w & 1;           // which 16-px strip of the 32
    const int q4 = lane >> 4, n16 = lane & 15;
    const int px = bxg * 32 + strip * 16 + n16;
    const int basepix = ho * WW + px;

    const int g   = h * 4 + q4;        // per-LANE offset group (B-frag k-block)

    floatx4 acc[4];
    #pragma unroll
    for (int ot = 0; ot < 4; ++ot)
        #pragma unroll
        for (int r = 0; r < 4; ++r)
            acc[ot][r] = h ? 0.f : bias[ot * 16 + q4 * 4 + r];

    const char*  ib   = (const char*)(in_t + (long)b * GG * HW * 8);
    const int    gsh  = g << 18;
    const float* offp = off + (b * 144 + g * 18) * HW + basepix;
    const float* mskp = msk + (b * 72  + g * 9 ) * HW + basepix;

    // ---- 9 taps: off/mask load -> gather -> interp -> B-frag -> 4 MFMA ----
    #pragma unroll
    for (int i = 0; i < 9; ++i) {
        const int ky = i / 3, kx = i - (i / 3) * 3;   // compile-time consts

        const float dy = offp[(2 * i) * HW];
        const float dx = offp[(2 * i + 1) * HW];
        const float m  = mskp[i * HW];

        const float py  = (float)(ho - 1 + ky) + dy;
        const float pxf = (float)(px - 1 + kx) + dx;
        const float y0f = floorf(py), x0f = floorf(pxf);
        const float ly = py - y0f, lx = pxf - x0f;
        const int y0 = (int)y0f, x0 = (int)x0f;
        const int y1 = y0 + 1,  x1 = x0 + 1;

        const float vy0 = (y0 >= 0 && y0 < HH) ? 1.f : 0.f;
        const float vy1 = (y1 >= 0 && y1 < HH) ? 1.f : 0.f;
        const float vx0 = (x0 >= 0 && x0 < WW) ? 1.f : 0.f;
        const float vx1 = (x1 >= 0 && x1 < WW) ? 1.f : 0.f;
        const int y0c = min(max(y0, 0), HH - 1), y1c = min(max(y1, 0), HH - 1);
        const int x0c = min(max(x0, 0), WW - 1), x1c = min(max(x1, 0), WW - 1);

        const float wy0 = (1.f - ly) * vy0 * m;
        const float wy1 = ly * vy1 * m;
        const float wx0 = (1.f - lx) * vx0;
        const float wx1 = lx * vx1;
        const float w00 = wy0 * wx0, w01 = wy0 * wx1;
        const float w10 = wy1 * wx0, w11 = wy1 * wx1;

        const int y0sh = gsh + (y0c << 11), y1sh = gsh + (y1c << 11);
        const int x0sh = x0c << 4, x1sh = x1c << 4;
        S8I u00, u01, u10, u11;
        u00.s = *(const short8*)(ib + (y0sh + x0sh));
        u01.s = *(const short8*)(ib + (y0sh + x1sh));
        u10.s = *(const short8*)(ib + (y1sh + x0sh));
        u11.s = *(const short8*)(ib + (y1sh + x1sh));

        const f32x2 W00 = {w00, w00}, W01 = {w01, w01};
        const f32x2 W10 = {w10, w10}, W11 = {w11, w11};
        S8I res;
        #pragma unroll
        for (int pc = 0; pc < 4; ++pc) {
            const int e00 = u00.i[pc], e01 = u01.i[pc];
            const int e10 = u10.i[pc], e11 = u11.i[pc];
            f32x2 a00 = {bflo(e00), bfhi(e00)};
            f32x2 a01 = {bflo(e01), bfhi(e01)};
            f32x2 a10 = {bflo(e10), bfhi(e10)};
            f32x2 a11 = {bflo(e11), bfhi(e11)};
            f32x2 v = a00 * W00;
            v += a01 * W01;
            v += a10 * W10;
            v += a11 * W11;
            res.i[pc] = (int)__builtin_amdgcn_perm(rnd2(v.y), rnd2(v.x), 0x07060302u);
        }

        // res.s IS the B-fragment for chunk (h,i); A-frags L2-hot global
        #pragma unroll
        for (int ot = 0; ot < 4; ++ot) {
            const short8 afr = *(const short8*)&wf[((h * 9 + i) * 4 + ot) * 512 + lane * 8];
            acc[ot] = __builtin_amdgcn_mfma_f32_16x16x32_bf16(afr, res.s, acc[ot], 0, 0, 0);
        }
    }

    // ---- combine K-halves: h=1 partials through LDS (conflict-free b32) ----
    if (h) {
        #pragma unroll
        for (int ot = 0; ot < 4; ++ot)
            #pragma unroll
            for (int r = 0; r < 4; ++r)
                s_red[strip][ot * 4 + r][lane] = acc[ot][r];
    }
    __syncthreads();
    if (!h) {
        #pragma unroll
        for (int ot = 0; ot < 4; ++ot)
            #pragma unroll
            for (int r = 0; r < 4; ++r)
                acc[ot][r] += s_red[strip][ot * 4 + r][lane];

        // ---- epilogue: o = ot*16 + q4*4 + r ----
        #pragma unroll
        for (int ot = 0; ot < 4; ++ot)
            #pragma unroll
            for (int r = 0; r < 4; ++r)
                out[((b * CO + ot * 16 + q4 * 4 + r) * HH + ho) * WW + px] = acc[ot][r];
    }
}

extern "C" void kernel_launch(void* const* d_in, const int* in_sizes, int n_in,
                              void* d_out, int out_size, void* d_ws, size_t ws_size,
                              hipStream_t stream) {
    const float* in   = (const float*)d_in[0];
    const float* off  = (const float*)d_in[1];
    const float* msk  = (const float*)d_in[2];
    const float* wt   = (const float*)d_in[3];
    const float* bias = (const float*)d_in[4];
    float* out = (float*)d_out;
    short* wf   = (short*)d_ws;            // 36864 shorts = 72 KB
    short* in_t = (short*)d_ws + 36864;    // 4*8*16384*8 shorts = 8 MB

    prep<<<144 + 2048, 256, 0, stream>>>(wt, in, wf, in_t);

    dcn_split<<<2048, 256, 0, stream>>>(in_t, off, msk, wf, bias, out);
}

// Round 10
// 133.651 us; speedup vs baseline: 1.4436x; 1.1597x over previous
//
#include <hip/hip_runtime.h>

#define HH 128
#define WW 128
#define CC 64
#define CO 64
#define BB 4
#define GG 8
#define CG 8
#define KK 9
#define HW (HH*WW)

typedef __attribute__((ext_vector_type(8))) short short8;
typedef __attribute__((ext_vector_type(4))) float floatx4;
typedef __attribute__((ext_vector_type(2))) float f32x2;

union S8I { short8 s; int i[4]; };
union FU { float f; unsigned u; };

__device__ inline short f2bf(float f) {
    FU v; v.f = f;
    return (short)((v.u + 0x7FFF + ((v.u >> 16) & 1)) >> 16);
}
__device__ inline unsigned rnd2(float f) {   // round-half-up bf16 in bits [31:16]
    FU v; v.f = f;
    return v.u + 0x8000u;
}
__device__ inline float bflo(int e) { union { int i; float f; } u; u.i = e << 16; return u.f; }
__device__ inline float bfhi(int e) { union { int i; float f; } u; u.i = e & 0xffff0000; return u.f; }

template<int N> struct Int { static constexpr int value = N; };

// ---- merged prep (unchanged) ----
// A-frag layout for the half-K GEMM: fid = (h*9+gc)*4 + ot,
//   wf[fid*512 + L*8 + j] = bf16(W[o=ot*16+(L&15)][g=h*4+(L>>4)][cg=j][kk=gc])
// Input NCHW f32 -> in_t[b][g][y*W+x][cg] bf16 (16B per pixel-group).
__global__ __launch_bounds__(256)
void prep(const float* __restrict__ wt, const float* __restrict__ in,
          short* __restrict__ wf, short* __restrict__ in_t) {
    const int bid = blockIdx.x;
    if (bid < 144) {
        const int tid = bid * 256 + threadIdx.x;   // < 36864 = 576*64
        const int j   = tid & 7;
        const int L   = (tid >> 3) & 63;
        const int fid = tid >> 9;                  // (h*9+gc)*4 + ot, 0..71
        const int ot  = fid & 3;
        const int gch = fid >> 2;                  // h*9 + gc, 0..17
        const int h   = gch / 9, gc = gch - h * 9;
        const int o   = ot * 16 + (L & 15);
        const int g   = h * 4 + (L >> 4);
        wf[tid] = f2bf(wt[o * 576 + (g * 8 + j) * 9 + gc]);
    } else {
        const int idx = bid - 144;                 // 2048 blocks: 64 x 8 x 4
        const int bx = idx & 63;
        const int g  = (idx >> 6) & 7;
        const int b  = idx >> 9;
        const int p  = bx * 256 + threadIdx.x;
        const float* src = in + (b * CC + g * CG) * HW + p;
        short8 v;
        #pragma unroll
        for (int cg = 0; cg < CG; ++cg) v[cg] = f2bf(src[cg * HW]);
        *(short8*)(in_t + ((b * GG + g) * HW + p) * 8) = v;
    }
}

// v9b: FORCED-MLP gather pipeline (macro-free rebuild of r9).
// Surviving model after r0-r8 (TA-throughput, LDS-gather, occupancy all
// falsified): scattered-gather latency x Little's law. The compiler held only
// ~6-12 gathers in flight in every source formulation. Here each gather is an
// inline-asm global_load_dwordx4 with "=&v" output: the allocator MUST keep
// all 36 per-wave loads live. Consume is gated by counted s_waitcnt
// vmcnt(4*(8-i)) ("n"-constraint via Int<I> lambda tags => genuine ICE) +
// sched_barrier(0) (rule-18 fence). vmcnt stream is clean: off/msk retire
// (via weight math) before gathers issue; A-frags come from LDS (lgkmcnt);
// stores are last. Outstanding per CU: 16 waves x 36 = 576 (~6x best prior).
__global__ __launch_bounds__(256, 2)
void dcn_mlp(const short* __restrict__ in_t, const float* __restrict__ off,
             const float* __restrict__ msk, const short* __restrict__ wf,
             const float* __restrict__ bias, float* __restrict__ out)
{
    __shared__ short s_wf[36 * 512];   // 36,864 B: ONE half's A-fragments

    const int t = threadIdx.x;

    // bijective XCD swizzle (1024 % 8 == 0)
    const int lin = (blockIdx.x & 7) * 128 + (blockIdx.x >> 3);
    const int b   = lin >> 8;          // 0..3
    const int rem = lin & 255;
    const int ho  = rem >> 1;          // 0..127
    const int bx  = rem & 1;           // 0..1

    const int w = t >> 6, lane = t & 63;
    const int q4 = lane >> 4, n16 = lane & 15;
    const int px = bx * 64 + w * 16 + n16;    // this lane's output pixel
    const int basepix = ho * WW + px;

    floatx4 acc[4];
    #pragma unroll
    for (int ot = 0; ot < 4; ++ot)
        #pragma unroll
        for (int r = 0; r < 4; ++r)
            acc[ot][r] = bias[ot * 16 + q4 * 4 + r];

    const char* ib = (const char*)(in_t + (long)b * GG * HW * 8);

    #pragma unroll
    for (int h = 0; h < 2; ++h) {
        // ---- stage this half's 36 A-frags into LDS ----
        if (h) __syncthreads();            // all waves done reading half 0
        #pragma unroll
        for (int k = 0; k < 9; ++k) {
            const int idx = (k * 256 + t) * 8;
            *(short8*)(s_wf + idx) = *(const short8*)(wf + h * 18432 + idx);
        }
        __syncthreads();                   // drains staging vmcnt too

        const int g   = h * 4 + q4;        // per-LANE group (B-frag k-block)
        const int gsh = g << 18;

        // ---- preload off/mask (27 coalesced loads) ----
        float pdy[9], pdx[9], pm[9];
        #pragma unroll
        for (int i = 0; i < 9; ++i) {
            const int offc = (b * 144 + g * 18 + i * 2) * HW + basepix;
            pdy[i] = off[offc];
            pdx[i] = off[offc + HW];
            pm[i]  = msk[(b * 72 + g * 9 + i) * HW + basepix];
        }

        // ---- weights + addresses for ALL 9 taps (consumes off/msk) ----
        float cw00[9], cw01[9], cw10[9], cw11[9];
        int o00[9], o01[9], o10[9], o11[9];
        #pragma unroll
        for (int i = 0; i < 9; ++i) {
            const int ky = i / 3, kx = i - (i / 3) * 3;   // consts

            const float py  = (float)(ho - 1 + ky) + pdy[i];
            const float pxf = (float)(px - 1 + kx) + pdx[i];
            const float y0f = floorf(py), x0f = floorf(pxf);
            const float ly = py - y0f, lx = pxf - x0f;
            const int y0 = (int)y0f, x0 = (int)x0f;
            const int y1 = y0 + 1,  x1 = x0 + 1;

            const float vy0 = (y0 >= 0 && y0 < HH) ? 1.f : 0.f;
            const float vy1 = (y1 >= 0 && y1 < HH) ? 1.f : 0.f;
            const float vx0 = (x0 >= 0 && x0 < WW) ? 1.f : 0.f;
            const float vx1 = (x1 >= 0 && x1 < WW) ? 1.f : 0.f;
            const int y0c = min(max(y0, 0), HH - 1), y1c = min(max(y1, 0), HH - 1);
            const int x0c = min(max(x0, 0), WW - 1), x1c = min(max(x1, 0), WW - 1);

            const float m = pm[i];
            const float wy0 = (1.f - ly) * vy0 * m;
            const float wy1 = ly * vy1 * m;
            const float wx0 = (1.f - lx) * vx0;
            const float wx1 = lx * vx1;
            cw00[i] = wy0 * wx0; cw01[i] = wy0 * wx1;
            cw10[i] = wy1 * wx0; cw11[i] = wy1 * wx1;

            const int y0sh = gsh + (y0c << 11), y1sh = gsh + (y1c << 11);
            const int x0sh = x0c << 4, x1sh = x1c << 4;
            o00[i] = y0sh + x0sh; o01[i] = y0sh + x1sh;
            o10[i] = y1sh + x0sh; o11[i] = y1sh + x1sh;
        }

        // ---- ISSUE: 36 forced-live gathers (allocator must hold 144 VGPRs) ----
        S8I u00[9], u01[9], u10[9], u11[9];
        #pragma unroll
        for (int i = 0; i < 9; ++i) {
            asm volatile("global_load_dwordx4 %0, %1, off"
                         : "=&v"(u00[i].s) : "v"(ib + o00[i]) : "memory");
            asm volatile("global_load_dwordx4 %0, %1, off"
                         : "=&v"(u01[i].s) : "v"(ib + o01[i]) : "memory");
            asm volatile("global_load_dwordx4 %0, %1, off"
                         : "=&v"(u10[i].s) : "v"(ib + o10[i]) : "memory");
            asm volatile("global_load_dwordx4 %0, %1, off"
                         : "=&v"(u11[i].s) : "v"(ib + o11[i]) : "memory");
        }

        // ---- CONSUME: counted vmcnt (4 loads retired per tap) ----
        auto consume = [&](auto tag) {
            constexpr int i  = decltype(tag)::value;
            constexpr int vm = 4 * (8 - i);
            asm volatile("s_waitcnt vmcnt(%0)" :: "n"(vm) : "memory");
            __builtin_amdgcn_sched_barrier(0);

            const f32x2 W00 = {cw00[i], cw00[i]}, W01 = {cw01[i], cw01[i]};
            const f32x2 W10 = {cw10[i], cw10[i]}, W11 = {cw11[i], cw11[i]};
            S8I res;
            #pragma unroll
            for (int pc = 0; pc < 4; ++pc) {
                const int e00 = u00[i].i[pc], e01 = u01[i].i[pc];
                const int e10 = u10[i].i[pc], e11 = u11[i].i[pc];
                f32x2 a00 = {bflo(e00), bfhi(e00)};
                f32x2 a01 = {bflo(e01), bfhi(e01)};
                f32x2 a10 = {bflo(e10), bfhi(e10)};
                f32x2 a11 = {bflo(e11), bfhi(e11)};
                f32x2 v = a00 * W00;
                v += a01 * W01;
                v += a10 * W10;
                v += a11 * W11;
                res.i[pc] = (int)__builtin_amdgcn_perm(rnd2(v.y), rnd2(v.x), 0x07060302u);
            }

            // res.s IS the B-fragment for chunk (h,i); A-frags via lgkmcnt
            #pragma unroll
            for (int ot = 0; ot < 4; ++ot) {
                const short8 afr = *(const short8*)&s_wf[(i * 4 + ot) * 512 + lane * 8];
                acc[ot] = __builtin_amdgcn_mfma_f32_16x16x32_bf16(afr, res.s, acc[ot], 0, 0, 0);
            }
        };
        consume(Int<0>{});
        consume(Int<1>{});
        consume(Int<2>{});
        consume(Int<3>{});
        consume(Int<4>{});
        consume(Int<5>{});
        consume(Int<6>{});
        consume(Int<7>{});
        consume(Int<8>{});
    }

    // ---- epilogue: o = ot*16 + q4*4 + r ----
    #pragma unroll
    for (int ot = 0; ot < 4; ++ot)
        #pragma unroll
        for (int r = 0; r < 4; ++r)
            out[((b * CO + ot * 16 + q4 * 4 + r) * HH + ho) * WW + px] = acc[ot][r];
}

extern "C" void kernel_launch(void* const* d_in, const int* in_sizes, int n_in,
                              void* d_out, int out_size, void* d_ws, size_t ws_size,
                              hipStream_t stream) {
    const float* in   = (const float*)d_in[0];
    const float* off  = (const float*)d_in[1];
    const float* msk  = (const float*)d_in[2];
    const float* wt   = (const float*)d_in[3];
    const float* bias = (const float*)d_in[4];
    float* out = (float*)d_out;
    short* wf   = (short*)d_ws;            // 36864 shorts = 72 KB
    short* in_t = (short*)d_ws + 36864;    // 4*8*16384*8 shorts = 8 MB

    prep<<<144 + 2048, 256, 0, stream>>>(wt, in, wf, in_t);

    dcn_mlp<<<1024, 256, 0, stream>>>(in_t, off, msk, wf, bias, out);
}